// Round 2
// baseline (522.360 us; speedup 1.0000x reference)
//
#include <hip/hip_runtime.h>
#include <hip/hip_bf16.h>
#include <cstdint>
#include <cstddef>

#define B_  64
#define S_  2048
#define E_  512
#define C_  512
#define H_  256

using f32x4 = __attribute__((ext_vector_type(4))) float;
using s16x8 = __attribute__((ext_vector_type(8))) short;

// packed fp32x4 -> bf16x4 (RNE)
__device__ __forceinline__ uint2 f4_to_bf4(float4 v) {
    __hip_bfloat162 lo = __float22bfloat162_rn(make_float2(v.x, v.y));
    __hip_bfloat162 hi = __float22bfloat162_rn(make_float2(v.z, v.w));
    union { __hip_bfloat162 b; unsigned u; } a, c;
    a.b = lo; c.b = hi;
    return make_uint2(a.u, c.u);
}

// 8 consecutive fp32 -> bf16x8 fragment (RNE), in-register
__device__ __forceinline__ s16x8 pack_bf8(float4 a, float4 b) {
    union { s16x8 v; uint2 u[2]; } r;
    r.u[0] = f4_to_bf4(a);
    r.u[1] = f4_to_bf4(b);
    return r.v;
}

// ---- merged prep: blocks 0..127 convert W_word to bf16; blocks 128..191 do
// cb[b][h] = ctx[b]@W_ctx[h]^T + b_ctx[h] + b_word[h] ----
__global__ void prep_kernel(const float* __restrict__ W, unsigned short* __restrict__ Wb,
                            const float* __restrict__ ctx, const float* __restrict__ Wc,
                            const float* __restrict__ bc, const float* __restrict__ bw,
                            float* __restrict__ cb) {
    __shared__ float row[C_];
    int blk = blockIdx.x, t = threadIdx.x;
    if (blk < 128) {
        int i = (blk * 256 + t) * 4;
        float4 v = *(const float4*)(W + i);
        *(uint2*)(Wb + i) = f4_to_bf4(v);
    } else {
        int b = blk - 128;
        row[t] = ctx[b * C_ + t];
        row[t + 256] = ctx[b * C_ + t + 256];
        __syncthreads();
        const float4* w4 = (const float4*)(Wc + (size_t)t * C_);
        const float4* x4 = (const float4*)row;
        float acc = 0.f;
        #pragma unroll 4
        for (int c = 0; c < C_ / 4; ++c) {
            float4 w = w4[c], x = x4[c];
            acc += w.x * x.x + w.y * x.y + w.z * x.z + w.w * x.w;
        }
        cb[b * H_ + t] = acc + bc[t] + bw[t];
    }
}

// ---- main: scores[b,s] = w_hidden . tanh(embeds[b,s]@W_word^T + cb[b]) ----
// De-staged streaming GEMM: no tile LDS, no K-loop barriers.
//  - B (Wb, 256 KB bf16) is L2-resident across all blocks: fragments load
//    directly from global (16 B/lane, contiguous) — LDS staging of L2-fit
//    data is pure overhead.
//  - A (embeds) streams from HBM as fp32 (2x float4/lane/fragment) and is
//    packed to bf16 in-register. Read x4 redundantly across the 4 n-waves;
//    the 3 extra reads hit L1/L2 (~18 TB/s aggregate, under the L2 ceiling).
//  - K-loop is pure loads+cvt+MFMA: compiler pipelines freely, no
//    vmcnt(0)-drain barriers quantizing the HBM stream.
// Bitwise-identical scores vs the staged version (same conversions, same
// MFMA order, same epilogue).
#define BM 64
#define BK 64

__global__ __launch_bounds__(256) void scores_kernel(
    const float* __restrict__ A,            // [B*S, E] fp32
    const unsigned short* __restrict__ Wb,  // [H, E] bf16
    const float* __restrict__ cb,           // [B, H]
    const float* __restrict__ wh,           // [H]
    const int*   __restrict__ lens,         // [B]
    float* __restrict__ scores)             // [B*S]
{
    __shared__ float sblk[BM];
    int t = threadIdx.x;
    int m0 = blockIdx.x * BM;
    int b  = m0 >> 11;   // /S_
    int ms = m0 & (S_ - 1);
    if (ms >= lens[b]) return;   // fully-masked slab: dead work

    int w = t >> 6, lane = t & 63, quad = lane >> 4, lm = lane & 15;
    int wn = w * 64;             // wave owns n = wn..wn+63, all m = 0..63

    if (t < BM) sblk[t] = 0.f;

    // per-thread row base pointers (k-invariant); k offsets become immediates
    const float* a_base[4];
    const unsigned short* b_base[4];
    #pragma unroll
    for (int i = 0; i < 4; ++i) {
        a_base[i] = A  + (size_t)(m0 + i * 16 + lm) * E_ + quad * 8;
        b_base[i] = Wb + (size_t)(wn + i * 16 + lm) * E_ + quad * 8;
    }

    f32x4 acc[4][4] = {};

    #pragma unroll 2
    for (int k0 = 0; k0 < E_; k0 += BK) {
        #pragma unroll
        for (int ks = 0; ks < 2; ++ks) {
            int ko = k0 + ks * 32;
            s16x8 bfr[4];
            #pragma unroll
            for (int i = 0; i < 4; ++i)
                bfr[i] = *(const s16x8*)(b_base[i] + ko);   // L2-hit, 16 B/lane
            #pragma unroll
            for (int mi = 0; mi < 4; ++mi) {
                const float* ap = a_base[mi] + ko;
                float4 a0 = *(const float4*)ap;             // HBM stream
                float4 a1 = *(const float4*)(ap + 4);
                s16x8 af = pack_bf8(a0, a1);
                #pragma unroll
                for (int ni = 0; ni < 4; ++ni)
                    acc[mi][ni] = __builtin_amdgcn_mfma_f32_16x16x32_bf16(
                        af, bfr[ni], acc[mi][ni], 0, 0, 0);
            }
        }
    }
    __syncthreads();   // sblk init visible before cross-wave atomics

    float wv[4], cbv[4];
    #pragma unroll
    for (int ni = 0; ni < 4; ++ni) {
        int n = wn + ni * 16 + lm;
        wv[ni]  = wh[n];
        cbv[ni] = cb[b * H_ + n];
    }
    #pragma unroll
    for (int mi = 0; mi < 4; ++mi) {
        #pragma unroll
        for (int r = 0; r < 4; ++r) {
            float p = 0.f;
            #pragma unroll
            for (int ni = 0; ni < 4; ++ni) {
                float x = acc[mi][ni][r] + cbv[ni];
                x = fminf(fmaxf(x, -15.f), 15.f);
                float e = __expf(2.f * x);
                float th = 1.f - 2.f * __builtin_amdgcn_rcpf(e + 1.f);
                p += wv[ni] * th;
            }
            #pragma unroll
            for (int off = 8; off >= 1; off >>= 1)
                p += __shfl_xor(p, off);
            if (lm == 0)
                atomicAdd(&sblk[mi * 16 + quad * 4 + r], p);
        }
    }
    __syncthreads();
    if (t < BM) scores[m0 + t] = sblk[t];
}

// ---- masked softmax over s<len; attn=0 for s>=len. Also zeroes feat[b,:]
// (wsum accumulates with atomics and runs after this in stream order).
__global__ void softmax_kernel(const int* __restrict__ lens, float* __restrict__ attn,
                               float* __restrict__ feat) {
    __shared__ float redm[4], redt[4];
    int b = blockIdx.x, t = threadIdx.x;
    int len = lens[b];
    float* sc = attn + (size_t)b * S_;
    feat[b * E_ + t] = 0.f;
    feat[b * E_ + 256 + t] = 0.f;
    float v[8];
    #pragma unroll
    for (int i = 0; i < 8; ++i) {
        int s = t + i * 256;
        v[i] = (s < len) ? sc[s] : -1e30f;
    }
    float m = -1e30f;
    #pragma unroll
    for (int i = 0; i < 8; ++i) m = fmaxf(m, v[i]);
    #pragma unroll
    for (int off = 32; off >= 1; off >>= 1) m = fmaxf(m, __shfl_xor(m, off));
    if ((t & 63) == 0) redm[t >> 6] = m;
    __syncthreads();
    m = fmaxf(fmaxf(redm[0], redm[1]), fmaxf(redm[2], redm[3]));
    float e[8]; float tm = 0.f;
    #pragma unroll
    for (int i = 0; i < 8; ++i) {
        int s = t + i * 256;
        e[i] = (s < len) ? __expf(v[i] - m) : 0.f;
        tm += e[i];
    }
    #pragma unroll
    for (int off = 32; off >= 1; off >>= 1) tm += __shfl_xor(tm, off);
    if ((t & 63) == 0) redt[t >> 6] = tm;
    __syncthreads();
    tm = redt[0] + redt[1] + redt[2] + redt[3];
    float sfac = 1.f / tm;
    #pragma unroll
    for (int i = 0; i < 8; ++i) {
        int s = t + i * 256;
        sc[s] = e[i] * sfac;
    }
}

// ---- attention_features[b,e] = sum_{s<len} attn[b,s]*embeds[b,s,e] ----
__global__ __launch_bounds__(512) void wsum_kernel(
    const float* __restrict__ A, const float* __restrict__ attn,
    const int* __restrict__ lens, float* __restrict__ out) {
    int b = blockIdx.y;
    int len = lens[b];
    int s0 = blockIdx.x * 128;
    if (s0 >= len) return;
    int send = s0 + 128; if (send > len) send = len;
    int t  = threadIdx.x;
    int e4 = t & 127;   // float4 column
    int sr = t >> 7;    // row group 0..3
    const float* ap = attn + (size_t)b * S_;
    f32x4 acc = {0.f, 0.f, 0.f, 0.f};
    const float* base = A + (size_t)b * S_ * E_;
    for (int s = s0 + sr; s < send; s += 4) {
        float wgt = ap[s];
        f32x4 v = *(const f32x4*)(base + (size_t)s * E_ + e4 * 4);
        acc += wgt * v;
    }
    __shared__ f32x4 red[4][128];
    red[sr][e4] = acc;
    __syncthreads();
    if (t < 128) {
        f32x4 tot = red[0][t] + red[1][t] + red[2][t] + red[3][t];
        float* o = out + (size_t)b * E_ + t * 4;
        atomicAdd(o + 0, tot[0]);
        atomicAdd(o + 1, tot[1]);
        atomicAdd(o + 2, tot[2]);
        atomicAdd(o + 3, tot[3]);
    }
}

extern "C" void kernel_launch(void* const* d_in, const int* in_sizes, int n_in,
                              void* d_out, int out_size, void* d_ws, size_t ws_size,
                              hipStream_t stream) {
    const float* embeds = (const float*)d_in[0];
    const int*   lens   = (const int*)d_in[1];
    const float* ctx    = (const float*)d_in[2];
    const float* Ww     = (const float*)d_in[3];
    const float* bw     = (const float*)d_in[4];
    const float* Wc     = (const float*)d_in[5];
    const float* bc     = (const float*)d_in[6];
    const float* wh     = (const float*)d_in[7];
    float* out  = (float*)d_out;
    float* feat = out;                 // [B, E]
    float* attn = out + B_ * E_;       // [B, S] (raw scores, then attn; 0 for s>=len)

    unsigned short* Wb = (unsigned short*)d_ws;                                  // 256 KB
    float* cb = (float*)((char*)d_ws + (size_t)H_ * E_ * sizeof(unsigned short)); // 64 KB

    prep_kernel<<<192, 256, 0, stream>>>(Ww, Wb, ctx, Wc, bc, bw, cb);
    scores_kernel<<<dim3(B_ * S_ / BM), 256, 0, stream>>>(embeds, Wb, cb, wh, lens, attn);
    softmax_kernel<<<B_, 256, 0, stream>>>(lens, attn, feat);
    wsum_kernel<<<dim3(S_ / 128, B_), 512, 0, stream>>>(embeds, attn, lens, feat);
}

// Round 3
// 418.864 us; speedup vs baseline: 1.2471x; 1.2471x over previous
//
#include <hip/hip_runtime.h>
#include <hip/hip_bf16.h>
#include <cstdint>
#include <cstddef>

#define B_  64
#define S_  2048
#define E_  512
#define C_  512
#define H_  256

using f32x4 = __attribute__((ext_vector_type(4))) float;
using s16x8 = __attribute__((ext_vector_type(8))) short;

// packed fp32x4 -> bf16x4 (RNE)
__device__ __forceinline__ uint2 f4_to_bf4(float4 v) {
    __hip_bfloat162 lo = __float22bfloat162_rn(make_float2(v.x, v.y));
    __hip_bfloat162 hi = __float22bfloat162_rn(make_float2(v.z, v.w));
    union { __hip_bfloat162 b; unsigned u; } a, c;
    a.b = lo; c.b = hi;
    return make_uint2(a.u, c.u);
}

// async global->LDS DMA, 16 B per lane; lds dest = wave-uniform base + lane*16
__device__ __forceinline__ void async16(const void* g, void* l) {
    __builtin_amdgcn_global_load_lds(
        (const __attribute__((address_space(1))) void*)g,
        (__attribute__((address_space(3))) void*)l,
        16, 0, 0);
}

// ---- merged prep: blocks 0..127 convert W_word to bf16; blocks 128..191 do
// cb[b][h] = ctx[b]@W_ctx[h]^T + b_ctx[h] + b_word[h] ----
__global__ void prep_kernel(const float* __restrict__ W, unsigned short* __restrict__ Wb,
                            const float* __restrict__ ctx, const float* __restrict__ Wc,
                            const float* __restrict__ bc, const float* __restrict__ bw,
                            float* __restrict__ cb) {
    __shared__ float row[C_];
    int blk = blockIdx.x, t = threadIdx.x;
    if (blk < 128) {
        int i = (blk * 256 + t) * 4;
        float4 v = *(const float4*)(W + i);
        *(uint2*)(Wb + i) = f4_to_bf4(v);
    } else {
        int b = blk - 128;
        row[t] = ctx[b * C_ + t];
        row[t + 256] = ctx[b * C_ + t + 256];
        __syncthreads();
        const float4* w4 = (const float4*)(Wc + (size_t)t * C_);
        const float4* x4 = (const float4*)row;
        float acc = 0.f;
        #pragma unroll 4
        for (int c = 0; c < C_ / 4; ++c) {
            float4 w = w4[c], x = x4[c];
            acc += w.x * x.x + w.y * x.y + w.z * x.z + w.w * x.w;
        }
        cb[b * H_ + t] = acc + bc[t] + bw[t];
    }
}

// ---- main: scores + fused flash-style slab partials ----
// Staged GEMM (round-0 known-good, 83 us): B via coalesced global_load_lds DMA
// into XOR-swizzled LDS; A via register roundtrip + convert-once into padded
// LDS. De-staged variant REGRESSED to 197 us (MFMA fragment gather = 64
// txns/instr, transaction-bound) — staging IS the coalescer here.
// New epilogue: per-slab softmax partials (m_l, t_l) + partial weighted
// feature W_l[e] = sum_r exp(v_r-m_l)*embeds[r,e] from an L2-hot coalesced
// re-read of the slab. Kills wsum_kernel's ~134 MB HBM re-read + softmax pass.
#define BM 128
#define BN 256
#define BK 64
#define LDT 72   // padded LDS row stride for A (shorts)

__global__ __launch_bounds__(512) void scores_kernel(
    const float* __restrict__ A,            // [B*S, E] fp32
    const unsigned short* __restrict__ Wb,  // [H, E] bf16
    const float* __restrict__ cb,           // [B, H]
    const float* __restrict__ wh,           // [H]
    const int*   __restrict__ lens,         // [B]
    float* __restrict__ scores,             // [B*S] raw scores
    float* __restrict__ Wpart,              // [B*S/BM, E] slab partial features
    float* __restrict__ mtpart)             // [B*S/BM, 2]  (m_l, t_l)
{
    __shared__ __align__(16) unsigned short At[BM * LDT];   // 18.4 KB, padded
    __shared__ __align__(16) unsigned short Bt[BN * 64];    // 32 KB, DMA target (no pad)
    __shared__ float sblk[BM];
    __shared__ float pblk[BM];
    int t = threadIdx.x;
    int m0 = blockIdx.x * BM;
    int b  = m0 >> 11;   // /S_
    int ms = m0 & (S_ - 1);
    int len = lens[b];
    if (ms >= len) return;   // fully-masked slab: dead work (finalize skips it)

    int w = t >> 6, lane = t & 63, quad = lane >> 4, lm = lane & 15;
    int wm = (w & 1) * 64, wn = (w >> 1) * 64;

    if (t < BM) sblk[t] = 0.f;

    f32x4 acc[4][4] = {};

    int arow = t >> 4, acol = (t & 15) * 4;  // A staging: 32 rows/sweep, 4 sweeps
    int la8 = lane >> 3, lc8 = lane & 7;     // B DMA: 8 rows/inst, 8 chunks/row

    for (int k0 = 0; k0 < E_; k0 += BK) {
        // B: 8 waves x 4 DMA insts -> 256 rows x 128 B (issued first, stays in flight)
        #pragma unroll
        for (int j = 0; j < 4; ++j) {
            int r  = (w << 5) + (j << 3) + la8;
            int cg = (lc8 ^ (r & 7)) << 3;               // swizzled global short offset
            async16(Wb + (size_t)r * E_ + k0 + cg,
                    (char*)Bt + (((w << 5) + (j << 3)) << 7));
        }
        // A: register roundtrip, convert once at staging
        #pragma unroll
        for (int i = 0; i < 4; ++i) {
            int r = arow + i * 32;
            float4 v = *(const float4*)(A + (size_t)(m0 + r) * E_ + k0 + acol);
            *(uint2*)(At + r * LDT + acol) = f4_to_bf4(v);
        }
        __syncthreads();
        #pragma unroll
        for (int ks = 0; ks < 2; ++ks) {
            s16x8 af[4], bfr[4];
            #pragma unroll
            for (int i = 0; i < 4; ++i)
                af[i] = *(const s16x8*)(At + (wm + i * 16 + lm) * LDT + ks * 32 + quad * 8);
            #pragma unroll
            for (int i = 0; i < 4; ++i) {
                int r = wn + i * 16 + lm;
                int c = (ks * 4 + quad) ^ (r & 7);
                bfr[i] = *(const s16x8*)(Bt + r * 64 + c * 8);
            }
            #pragma unroll
            for (int mi = 0; mi < 4; ++mi)
                #pragma unroll
                for (int ni = 0; ni < 4; ++ni)
                    acc[mi][ni] = __builtin_amdgcn_mfma_f32_16x16x32_bf16(
                        af[mi], bfr[ni], acc[mi][ni], 0, 0, 0);
        }
        __syncthreads();
    }

    float wv[4], cbv[4];
    #pragma unroll
    for (int ni = 0; ni < 4; ++ni) {
        int n = wn + ni * 16 + lm;
        wv[ni]  = wh[n];
        cbv[ni] = cb[b * H_ + n];
    }
    #pragma unroll
    for (int mi = 0; mi < 4; ++mi) {
        #pragma unroll
        for (int r = 0; r < 4; ++r) {
            float p = 0.f;
            #pragma unroll
            for (int ni = 0; ni < 4; ++ni) {
                float x = acc[mi][ni][r] + cbv[ni];
                x = fminf(fmaxf(x, -15.f), 15.f);
                float e = __expf(2.f * x);
                float th = 1.f - 2.f * __builtin_amdgcn_rcpf(e + 1.f);
                p += wv[ni] * th;
            }
            #pragma unroll
            for (int off = 8; off >= 1; off >>= 1)
                p += __shfl_xor(p, off);
            if (lm == 0)
                atomicAdd(&sblk[wm + mi * 16 + quad * 4 + r], p);
        }
    }
    __syncthreads();
    if (t < BM) scores[m0 + t] = sblk[t];   // raw scores (finalize normalizes attn)

    // ---- fused epilogue: slab softmax partials + partial weighted feature ----
    int nvalid = len - ms; if (nvalid > BM) nvalid = BM;   // >= 1 here
    float m_l = -1e30f;
    #pragma unroll 16
    for (int r = 0; r < BM; ++r) {
        float sv = (r < nvalid) ? sblk[r] : -1e30f;
        m_l = fmaxf(m_l, sv);
    }
    if (t < BM) pblk[t] = (t < nvalid) ? __expf(sblk[t] - m_l) : 0.f;
    __syncthreads();
    float t_l = 0.f;
    #pragma unroll 16
    for (int r = 0; r < BM; ++r) t_l += pblk[r];
    // W_l[t] = sum_r pblk[r] * A[m0+r][t]; coalesced 2 KB/row, slab is L2-hot
    float accw = 0.f;
    const float* ab = A + (size_t)m0 * E_ + t;
    #pragma unroll 8
    for (int r = 0; r < BM; ++r)
        accw += pblk[r] * ab[(size_t)r * E_];   // pblk=0 pads masked rows
    Wpart[(size_t)blockIdx.x * E_ + t] = accw;
    if (t == 0) {
        mtpart[blockIdx.x * 2 + 0] = m_l;
        mtpart[blockIdx.x * 2 + 1] = t_l;
    }
}

// ---- finalize: merge slab partials per batch; write feat + normalized attn ----
__global__ __launch_bounds__(512) void finalize_kernel(
    const int* __restrict__ lens, const float* __restrict__ Wpart,
    const float* __restrict__ mtpart,
    float* __restrict__ attn,    // holds raw scores on entry; rewritten
    float* __restrict__ feat)
{
    int b = blockIdx.x, t = threadIdx.x;
    int len = lens[b];
    int L = (len + BM - 1) / BM;       // active slabs, 1..16
    int base = b * (S_ / BM);
    float M = -1e30f;
    for (int l = 0; l < L; ++l) M = fmaxf(M, mtpart[(base + l) * 2]);
    float T = 0.f;
    for (int l = 0; l < L; ++l)
        T += __expf(mtpart[(base + l) * 2] - M) * mtpart[(base + l) * 2 + 1];
    float inv = 1.f / T;
    // feat[b][t] = sum_l e^{m_l-M} * W_l[t] / T
    float acc = 0.f;
    for (int l = 0; l < L; ++l)
        acc += __expf(mtpart[(base + l) * 2] - M) * Wpart[(size_t)(base + l) * E_ + t];
    feat[b * E_ + t] = acc * inv;
    // attn[b][s] = e^{v-M}/T for s<len else 0
    float* sc = attn + (size_t)b * S_;
    #pragma unroll
    for (int i = 0; i < 4; ++i) {
        int s = t + i * 512;
        float v = sc[s];
        sc[s] = (s < len) ? __expf(v - M) * inv : 0.f;
    }
}

extern "C" void kernel_launch(void* const* d_in, const int* in_sizes, int n_in,
                              void* d_out, int out_size, void* d_ws, size_t ws_size,
                              hipStream_t stream) {
    const float* embeds = (const float*)d_in[0];
    const int*   lens   = (const int*)d_in[1];
    const float* ctx    = (const float*)d_in[2];
    const float* Ww     = (const float*)d_in[3];
    const float* bw     = (const float*)d_in[4];
    const float* Wc     = (const float*)d_in[5];
    const float* bc     = (const float*)d_in[6];
    const float* wh     = (const float*)d_in[7];
    float* out  = (float*)d_out;
    float* feat = out;                 // [B, E]
    float* attn = out + B_ * E_;       // [B, S] raw scores, then attn; 0 for s>=len

    char* ws = (char*)d_ws;
    unsigned short* Wb = (unsigned short*)ws;                         // 256 KB
    float* cb     = (float*)(ws + 256 * 1024);                        // 64 KB
    float* Wpart  = (float*)(ws + 320 * 1024);                        // 1024*512*4 = 2 MB
    float* mtpart = (float*)(ws + 320 * 1024 + 2 * 1024 * 1024);      // 8 KB

    prep_kernel<<<192, 256, 0, stream>>>(Ww, Wb, ctx, Wc, bc, bw, cb);
    scores_kernel<<<dim3(B_ * S_ / BM), 512, 0, stream>>>(embeds, Wb, cb, wh, lens,
                                                          attn, Wpart, mtpart);
    finalize_kernel<<<B_, 512, 0, stream>>>(lens, Wpart, mtpart, attn, feat);
}